// Round 3
// baseline (925.905 us; speedup 1.0000x reference)
//
#include <hip/hip_runtime.h>
#include <hip/hip_bf16.h>

#define NROWS 131072
#define KC 1024
#define DD 128
#define MARGIN 1e-3f

typedef __attribute__((ext_vector_type(8))) short short8;
typedef __attribute__((ext_vector_type(4))) float f32x4;

__device__ inline short f2bf_hi(float f) {
  unsigned u = __builtin_bit_cast(unsigned, f);
  u += 0x7fffu + ((u >> 16) & 1u);   // round-to-nearest-even
  return (short)(u >> 16);
}
__device__ inline float bf2f(short s) {
  unsigned u = ((unsigned)(unsigned short)s) << 16;
  return __builtin_bit_cast(float, u);
}

// Prep: embedding -> fragment-ordered bf16 hi/lo + exact row norms; zero loss slot.
// Fragment order: idx = ((c*4 + s)*64 + l), lane l = q*16+n holds e[16c+n][32s+8q+j], j=0..7
__global__ void vq_prep(const float* __restrict__ E, short* __restrict__ EH,
                        short* __restrict__ EL, float* __restrict__ SE,
                        float* __restrict__ out) {
  int b = blockIdx.x, t = threadIdx.x;
  if (b < 64) {
    int idx = b * 256 + t;
    int s = (idx >> 6) & 3, l = idx & 63;
    int c = idx >> 8;
    int q = l >> 4, n = l & 15;
    const float* src = E + (16 * c + n) * DD + 32 * s + 8 * q;
    short8 h, lo;
#pragma unroll
    for (int j = 0; j < 8; ++j) {
      float x = src[j];
      short hb = f2bf_hi(x);
      h[j] = hb;
      lo[j] = f2bf_hi(x - bf2f(hb));
    }
    *(short8*)(EH + idx * 8) = h;
    *(short8*)(EL + idx * 8) = lo;
  } else {
    if (t == 0) out[0] = 0.f;
    for (int k = t; k < KC; k += 256) {
      double acc = 0.0;
      const float* er = E + k * DD;
      for (int i = 0; i < DD; ++i) { double v = (double)er[i]; acc += v * v; }
      SE[k] = (float)acc;
    }
  }
}

// Argmin: 128 rows/block, 16 chunks of 64 codes; 3-pass hi/lo bf16 MFMA,
// top-2 tracking, exact fp64 repair for near-ties; writes IDX[row].
__global__ __launch_bounds__(256, 3) void vq_argmin(
    const float* __restrict__ X, const float* __restrict__ E,
    const short* __restrict__ EH, const short* __restrict__ EL,
    const float* __restrict__ SE, int* __restrict__ IDX) {
  __shared__ __align__(16) short lbh[8192];   // 16 KB: B-hi chunk (4 tiles x 4 steps x 64 lanes x 8)
  __shared__ __align__(16) short lbl[8192];   // 16 KB: B-lo chunk
  __shared__ int lidx[128];
  __shared__ int lflag[128];
  __shared__ int lany;
  __shared__ float lx[128];
  __shared__ float lrv[256];
  __shared__ int lri[256];
  __shared__ float lsx;

  const int tid = threadIdx.x;
  const int w = tid >> 6, l = tid & 63, q = l >> 4, n = l & 15;
  const int row_base = blockIdx.x * 128;
  if (tid == 0) lany = 0;

  // ---- A fragments: wave w owns rows row_base+32w .. +32 (2 tiles of 16) ----
  // A[m=lane&15][k=quad*8+j]; keep all 4 k-steps (D=128) hi+lo in registers.
  short8 ah[2][4], al[2][4];
#pragma unroll
  for (int mt = 0; mt < 2; ++mt) {
    const float* xp = X + (row_base + 32 * w + 16 * mt + n) * DD + 8 * q;
#pragma unroll
    for (int s = 0; s < 4; ++s) {
      f32x4 x0 = *(const f32x4*)(xp + 32 * s);
      f32x4 x1 = *(const f32x4*)(xp + 32 * s + 4);
#pragma unroll
      for (int j = 0; j < 4; ++j) {
        short hb = f2bf_hi(x0[j]);
        ah[mt][s][j] = hb;
        al[mt][s][j] = f2bf_hi(x0[j] - bf2f(hb));
        short hb2 = f2bf_hi(x1[j]);
        ah[mt][s][j + 4] = hb2;
        al[mt][s][j + 4] = f2bf_hi(x1[j] - bf2f(hb2));
      }
    }
  }

  // per-lane running top-2 (score = dot - |e|^2/2, maximize) per row-slot (mt,reg)
  float bestv[8], secv[8];
  int besti[8];
#pragma unroll
  for (int i = 0; i < 8; ++i) { bestv[i] = -3e38f; secv[i] = -3e38f; besti[i] = 0; }

  for (int cc = 0; cc < 16; ++cc) {
    {  // stage B chunk (16 KB hi + 16 KB lo) into LDS
      const short8* gh = (const short8*)(EH + cc * 8192);
      const short8* gl = (const short8*)(EL + cc * 8192);
      short8* dh = (short8*)lbh;
      short8* dl = (short8*)lbl;
#pragma unroll
      for (int i = 0; i < 4; ++i) {
        int u = i * 256 + tid;
        dh[u] = gh[u];
        dl[u] = gl[u];
      }
    }
    __syncthreads();

    f32x4 acc[2][4];
#pragma unroll
    for (int mt = 0; mt < 2; ++mt)
#pragma unroll
      for (int nt = 0; nt < 4; ++nt) acc[mt][nt] = (f32x4){0.f, 0.f, 0.f, 0.f};

#pragma unroll
    for (int nt = 0; nt < 4; ++nt) {
#pragma unroll
      for (int s = 0; s < 4; ++s) {
        short8 bh  = *(const short8*)(lbh + ((nt * 4 + s) * 64 + l) * 8);
        short8 blo = *(const short8*)(lbl + ((nt * 4 + s) * 64 + l) * 8);
        acc[0][nt] = __builtin_amdgcn_mfma_f32_16x16x32_bf16(ah[0][s], bh,  acc[0][nt], 0, 0, 0);
        acc[1][nt] = __builtin_amdgcn_mfma_f32_16x16x32_bf16(ah[1][s], bh,  acc[1][nt], 0, 0, 0);
        acc[0][nt] = __builtin_amdgcn_mfma_f32_16x16x32_bf16(al[0][s], bh,  acc[0][nt], 0, 0, 0);
        acc[1][nt] = __builtin_amdgcn_mfma_f32_16x16x32_bf16(al[1][s], bh,  acc[1][nt], 0, 0, 0);
        acc[0][nt] = __builtin_amdgcn_mfma_f32_16x16x32_bf16(ah[0][s], blo, acc[0][nt], 0, 0, 0);
        acc[1][nt] = __builtin_amdgcn_mfma_f32_16x16x32_bf16(ah[1][s], blo, acc[1][nt], 0, 0, 0);
      }
    }
    __syncthreads();  // LDS reuse next chunk

    // fold chunk scores into running top-2 (C layout: col = lane&15, row = quad*4+reg)
#pragma unroll
    for (int nt = 0; nt < 4; ++nt) {
      int k = cc * 64 + nt * 16 + n;
      float hse = 0.5f * SE[k];
#pragma unroll
      for (int mt = 0; mt < 2; ++mt)
#pragma unroll
        for (int r = 0; r < 4; ++r) {
          float sc = acc[mt][nt][r] - hse;
          int slot = mt * 4 + r;
          bool gt = sc > bestv[slot];
          secv[slot] = gt ? bestv[slot] : fmaxf(secv[slot], sc);
          if (gt) { bestv[slot] = sc; besti[slot] = k; }
        }
    }
  }

  // cross-lane top-2 merge over the 16 column-lanes of each quad (disjoint k-sets)
#pragma unroll
  for (int slot = 0; slot < 8; ++slot) {
    float v = bestv[slot], s2 = secv[slot];
    int bi = besti[slot];
#pragma unroll
    for (int m = 1; m <= 8; m <<= 1) {
      float v2 = __shfl_xor(v, m, 64);
      float sv2 = __shfl_xor(s2, m, 64);
      int i2 = __shfl_xor(bi, m, 64);
      float ns = fmaxf(fminf(v, v2), fmaxf(s2, sv2));
      if (v2 > v || (v2 == v && i2 < bi)) { v = v2; bi = i2; }
      s2 = ns;
    }
    if (n == 0) {
      int mt = slot >> 2, r = slot & 3;
      int rl = 32 * w + 16 * mt + 4 * q + r;
      int f = (v - s2) <= MARGIN;
      lidx[rl] = bi;
      lflag[rl] = f;
      if (f) lany = 1;
    }
  }
  __syncthreads();

  // ---- repair flagged rows: exact fp64 dots, numpy-rounding-emulated distances ----
  if (lany) {
    for (int rl = 0; rl < 128; ++rl) {
      if (lflag[rl] == 0) continue;           // uniform branch (LDS value)
      if (tid < DD) lx[tid] = X[(row_base + rl) * DD + tid];
      __syncthreads();
      if (tid == 0) {
        double sx = 0.0;
        for (int i = 0; i < DD; ++i) { double v = (double)lx[i]; sx += v * v; }
        lsx = (float)sx;
      }
      __syncthreads();
      float dmin = 3e38f; int kmin = 0;
      for (int kk = tid; kk < KC; kk += 256) {
        double dot = 0.0;
        const float* er = E + kk * DD;
        for (int i = 0; i < DD; ++i) dot += (double)lx[i] * (double)er[i];
        float a = lsx + SE[kk];
        float b2 = (float)(2.0 * dot);
        float dnp = a - b2;                   // RN(RN(sx+se) - RN(2 dot)) like np
        if (dnp < dmin) { dmin = dnp; kmin = kk; }
      }
      lrv[tid] = dmin; lri[tid] = kmin;
      __syncthreads();
      if (tid == 0) {
        float dm = lrv[0]; int km = lri[0];
        for (int t2 = 1; t2 < 256; ++t2)
          if (lrv[t2] < dm || (lrv[t2] == dm && lri[t2] < km)) { dm = lrv[t2]; km = lri[t2]; }
        lidx[rl] = km;
      }
      __syncthreads();
    }
  }
  __syncthreads();

  if (tid < 128) IDX[row_base + tid] = lidx[tid];
}

// Output: pure streaming. 64 rows/block (16 per wave): quantized_st, one-hot,
// loss partial -> atomicAdd. LDS-free, high occupancy, nontemporal stores.
__global__ __launch_bounds__(256) void vq_out(
    const float* __restrict__ X, const float* __restrict__ E,
    const int* __restrict__ IDX, float* __restrict__ out) {
  __shared__ float lloss[4];
  const int tid = threadIdx.x;
  const int w = tid >> 6, l = tid & 63;
  const int row0 = blockIdx.x * 64 + w * 16;
  const int encb = 1 + NROWS * DD;

  float lp = 0.f;
  for (int i = 0; i < 16; ++i) {
    int row = row0 + i;
    int idx = IDX[row];
    float x0 = X[row * DD + l];
    float x1 = X[row * DD + 64 + l];
    float e0 = E[idx * DD + l];
    float e1 = E[idx * DD + 64 + l];
    float d0 = e0 - x0, d1 = e1 - x1;
    __builtin_nontemporal_store(x0 + d0, out + 1 + row * DD + l);       // straight-through
    __builtin_nontemporal_store(x1 + d1, out + 1 + row * DD + 64 + l);
    lp += d0 * d0 + d1 * d1;
    float* ob = out + encb + row * KC;      // element offset = 1 mod 4
    if (l < 3) __builtin_nontemporal_store((l == idx) ? 1.f : 0.f, ob + l);
    for (int c = l; c < 255; c += 64) {     // ob+3 is 16B-aligned
      int eb = 3 + 4 * c;
      f32x4 v;
      v[0] = (eb     == idx) ? 1.f : 0.f;
      v[1] = (eb + 1 == idx) ? 1.f : 0.f;
      v[2] = (eb + 2 == idx) ? 1.f : 0.f;
      v[3] = (eb + 3 == idx) ? 1.f : 0.f;
      __builtin_nontemporal_store(v, (f32x4*)(ob + eb));
    }
    if (l == 63) __builtin_nontemporal_store((1023 == idx) ? 1.f : 0.f, ob + 1023);
  }
#pragma unroll
  for (int m = 1; m < 64; m <<= 1) lp += __shfl_xor(lp, m, 64);
  if (l == 0) lloss[w] = lp;
  __syncthreads();
  if (tid == 0) {
    float t = (lloss[0] + lloss[1] + lloss[2] + lloss[3]) *
              (1.25f / ((float)NROWS * (float)DD));
    atomicAdd(out, t);   // loss = q_latent + 0.25*e_latent = 1.25*mean
  }
}

extern "C" void kernel_launch(void* const* d_in, const int* in_sizes, int n_in,
                              void* d_out, int out_size, void* d_ws, size_t ws_size,
                              hipStream_t stream) {
  const float* X = (const float*)d_in[0];        // c_input [131072,128] fp32
  const float* E = (const float*)d_in[1];        // embedding [1024,128] fp32
  float* out = (float*)d_out;                    // [loss | quantized_st | encodings]
  short* EH = (short*)d_ws;                      // 256 KB bf16-hi fragments
  short* EL = EH + KC * DD;                      // 256 KB bf16-lo fragments
  float* SE = (float*)(EL + KC * DD);            // 4 KB row norms
  int* IDX = (int*)(SE + KC);                    // 512 KB argmin indices
  vq_prep<<<65, 256, 0, stream>>>(E, EH, EL, SE, out);
  vq_argmin<<<NROWS / 128, 256, 0, stream>>>(X, E, EH, EL, SE, IDX);
  vq_out<<<NROWS / 64, 256, 0, stream>>>(X, E, IDX, out);
}

// Round 4
// 908.720 us; speedup vs baseline: 1.0189x; 1.0189x over previous
//
#include <hip/hip_runtime.h>
#include <hip/hip_bf16.h>

#define NROWS 131072
#define KC 1024
#define DD 128
#define MARGIN 1e-3f

typedef __attribute__((ext_vector_type(8))) short short8;
typedef __attribute__((ext_vector_type(4))) float f32x4;

__device__ inline short f2bf_hi(float f) {
  unsigned u = __builtin_bit_cast(unsigned, f);
  u += 0x7fffu + ((u >> 16) & 1u);   // round-to-nearest-even
  return (short)(u >> 16);
}
__device__ inline float bf2f(short s) {
  unsigned u = ((unsigned)(unsigned short)s) << 16;
  return __builtin_bit_cast(float, u);
}

// Prep: embedding -> fragment-ordered bf16 hi/lo + exact row norms; zero loss slot.
// Fragment order: idx = ((c*4 + s)*64 + l), lane l = q*16+n holds e[16c+n][32s+8q+j], j=0..7
__global__ void vq_prep(const float* __restrict__ E, short* __restrict__ EH,
                        short* __restrict__ EL, float* __restrict__ SE,
                        float* __restrict__ out) {
  int b = blockIdx.x, t = threadIdx.x;
  if (b < 64) {
    int idx = b * 256 + t;
    int s = (idx >> 6) & 3, l = idx & 63;
    int c = idx >> 8;
    int q = l >> 4, n = l & 15;
    const float* src = E + (16 * c + n) * DD + 32 * s + 8 * q;
    short8 h, lo;
#pragma unroll
    for (int j = 0; j < 8; ++j) {
      float x = src[j];
      short hb = f2bf_hi(x);
      h[j] = hb;
      lo[j] = f2bf_hi(x - bf2f(hb));
    }
    *(short8*)(EH + idx * 8) = h;
    *(short8*)(EL + idx * 8) = lo;
  } else {
    if (t == 0) out[0] = 0.f;
    for (int k = t; k < KC; k += 256) {
      double acc = 0.0;
      const float* er = E + k * DD;
      for (int i = 0; i < DD; ++i) { double v = (double)er[i]; acc += v * v; }
      SE[k] = (float)acc;
    }
  }
}

// Fused: argmin (3-pass hi/lo bf16 MFMA over 16 chunks of 64 codes, top-2 +
// exact repair) + light output (quantized_st, one 1.0 per row, loss).
// Encodings zeros are produced by a hipMemsetAsync before this kernel.
__global__ __launch_bounds__(256, 4) void vq_main(
    const float* __restrict__ X, const float* __restrict__ E,
    const short* __restrict__ EH, const short* __restrict__ EL,
    const float* __restrict__ SE, float* __restrict__ out) {
  __shared__ __align__(16) short lbh[8192];   // 16 KB: B-hi chunk (4 tiles x 4 steps x 64 lanes x 8)
  __shared__ __align__(16) short lbl[8192];   // 16 KB: B-lo chunk
  __shared__ int lidx[128];
  __shared__ int lflag[128];
  __shared__ int lany;
  __shared__ float lx[128];
  __shared__ float lrv[256];
  __shared__ int lri[256];
  __shared__ float lsx;
  __shared__ float lloss[4];

  const int tid = threadIdx.x;
  const int w = tid >> 6, l = tid & 63, q = l >> 4, n = l & 15;
  const int row_base = blockIdx.x * 128;
  if (tid == 0) lany = 0;

  // ---- A fragments: wave w owns rows row_base+32w .. +32 (2 tiles of 16) ----
  // A[m=lane&15][k=quad*8+j]; keep all 4 k-steps (D=128) hi+lo in registers.
  short8 ah[2][4], al[2][4];
#pragma unroll
  for (int mt = 0; mt < 2; ++mt) {
    const float* xp = X + (row_base + 32 * w + 16 * mt + n) * DD + 8 * q;
#pragma unroll
    for (int s = 0; s < 4; ++s) {
      f32x4 x0 = *(const f32x4*)(xp + 32 * s);
      f32x4 x1 = *(const f32x4*)(xp + 32 * s + 4);
#pragma unroll
      for (int j = 0; j < 4; ++j) {
        short hb = f2bf_hi(x0[j]);
        ah[mt][s][j] = hb;
        al[mt][s][j] = f2bf_hi(x0[j] - bf2f(hb));
        short hb2 = f2bf_hi(x1[j]);
        ah[mt][s][j + 4] = hb2;
        al[mt][s][j + 4] = f2bf_hi(x1[j] - bf2f(hb2));
      }
    }
  }

  // per-lane running top-2 (score = dot - |e|^2/2, maximize) per row-slot (mt,reg)
  float bestv[8], secv[8];
  int besti[8];
#pragma unroll
  for (int i = 0; i < 8; ++i) { bestv[i] = -3e38f; secv[i] = -3e38f; besti[i] = 0; }

  for (int cc = 0; cc < 16; ++cc) {
    {  // stage B chunk (16 KB hi + 16 KB lo) into LDS
      const short8* gh = (const short8*)(EH + cc * 8192);
      const short8* gl = (const short8*)(EL + cc * 8192);
      short8* dh = (short8*)lbh;
      short8* dl = (short8*)lbl;
#pragma unroll
      for (int i = 0; i < 4; ++i) {
        int u = i * 256 + tid;
        dh[u] = gh[u];
        dl[u] = gl[u];
      }
    }
    __syncthreads();

    f32x4 acc[2][4];
#pragma unroll
    for (int mt = 0; mt < 2; ++mt)
#pragma unroll
      for (int nt = 0; nt < 4; ++nt) acc[mt][nt] = (f32x4){0.f, 0.f, 0.f, 0.f};

#pragma unroll
    for (int nt = 0; nt < 4; ++nt) {
#pragma unroll
      for (int s = 0; s < 4; ++s) {
        short8 bh  = *(const short8*)(lbh + ((nt * 4 + s) * 64 + l) * 8);
        short8 blo = *(const short8*)(lbl + ((nt * 4 + s) * 64 + l) * 8);
        acc[0][nt] = __builtin_amdgcn_mfma_f32_16x16x32_bf16(ah[0][s], bh,  acc[0][nt], 0, 0, 0);
        acc[1][nt] = __builtin_amdgcn_mfma_f32_16x16x32_bf16(ah[1][s], bh,  acc[1][nt], 0, 0, 0);
        acc[0][nt] = __builtin_amdgcn_mfma_f32_16x16x32_bf16(al[0][s], bh,  acc[0][nt], 0, 0, 0);
        acc[1][nt] = __builtin_amdgcn_mfma_f32_16x16x32_bf16(al[1][s], bh,  acc[1][nt], 0, 0, 0);
        acc[0][nt] = __builtin_amdgcn_mfma_f32_16x16x32_bf16(ah[0][s], blo, acc[0][nt], 0, 0, 0);
        acc[1][nt] = __builtin_amdgcn_mfma_f32_16x16x32_bf16(ah[1][s], blo, acc[1][nt], 0, 0, 0);
      }
    }
    __syncthreads();  // LDS reuse next chunk

    // fold chunk scores into running top-2 (C layout: col = lane&15, row = quad*4+reg)
#pragma unroll
    for (int nt = 0; nt < 4; ++nt) {
      int k = cc * 64 + nt * 16 + n;
      float hse = 0.5f * SE[k];
#pragma unroll
      for (int mt = 0; mt < 2; ++mt)
#pragma unroll
        for (int r = 0; r < 4; ++r) {
          float sc = acc[mt][nt][r] - hse;
          int slot = mt * 4 + r;
          bool gt = sc > bestv[slot];
          secv[slot] = gt ? bestv[slot] : fmaxf(secv[slot], sc);
          if (gt) { bestv[slot] = sc; besti[slot] = k; }
        }
    }
  }

  // cross-lane top-2 merge over the 16 column-lanes of each quad (disjoint k-sets)
#pragma unroll
  for (int slot = 0; slot < 8; ++slot) {
    float v = bestv[slot], s2 = secv[slot];
    int bi = besti[slot];
#pragma unroll
    for (int m = 1; m <= 8; m <<= 1) {
      float v2 = __shfl_xor(v, m, 64);
      float sv2 = __shfl_xor(s2, m, 64);
      int i2 = __shfl_xor(bi, m, 64);
      float ns = fmaxf(fminf(v, v2), fmaxf(s2, sv2));
      if (v2 > v || (v2 == v && i2 < bi)) { v = v2; bi = i2; }
      s2 = ns;
    }
    if (n == 0) {
      int mt = slot >> 2, r = slot & 3;
      int rl = 32 * w + 16 * mt + 4 * q + r;
      int f = (v - s2) <= MARGIN;
      lidx[rl] = bi;
      lflag[rl] = f;
      if (f) lany = 1;
    }
  }
  __syncthreads();

  // ---- repair flagged rows: exact fp64 dots, numpy-rounding-emulated distances ----
  if (lany) {
    for (int rl = 0; rl < 128; ++rl) {
      if (lflag[rl] == 0) continue;           // uniform branch (LDS value)
      if (tid < DD) lx[tid] = X[(row_base + rl) * DD + tid];
      __syncthreads();
      if (tid == 0) {
        double sx = 0.0;
        for (int i = 0; i < DD; ++i) { double v = (double)lx[i]; sx += v * v; }
        lsx = (float)sx;
      }
      __syncthreads();
      float dmin = 3e38f; int kmin = 0;
      for (int kk = tid; kk < KC; kk += 256) {
        double dot = 0.0;
        const float* er = E + kk * DD;
        for (int i = 0; i < DD; ++i) dot += (double)lx[i] * (double)er[i];
        float a = lsx + SE[kk];
        float b2 = (float)(2.0 * dot);
        float dnp = a - b2;                   // RN(RN(sx+se) - RN(2 dot)) like np
        if (dnp < dmin) { dmin = dnp; kmin = kk; }
      }
      lrv[tid] = dmin; lri[tid] = kmin;
      __syncthreads();
      if (tid == 0) {
        float dm = lrv[0]; int km = lri[0];
        for (int t2 = 1; t2 < 256; ++t2)
          if (lrv[t2] < dm || (lrv[t2] == dm && lri[t2] < km)) { dm = lrv[t2]; km = lri[t2]; }
        lidx[rl] = km;
      }
      __syncthreads();
    }
  }
  __syncthreads();

  // ---- light outputs: quantized_st, single 1.0 per row, loss partial ----
  float lp = 0.f;
  const int encb = 1 + NROWS * DD;
  for (int rl = w; rl < 128; rl += 4) {
    int row = row_base + rl;
    int idx = lidx[rl];
    float x0 = X[row * DD + l];
    float x1 = X[row * DD + 64 + l];
    float e0 = E[idx * DD + l];
    float e1 = E[idx * DD + 64 + l];
    float d0 = e0 - x0, d1 = e1 - x1;
    __builtin_nontemporal_store(x0 + d0, out + 1 + row * DD + l);       // straight-through
    __builtin_nontemporal_store(x1 + d1, out + 1 + row * DD + 64 + l);
    lp += d0 * d0 + d1 * d1;
    if (l == 0) out[encb + row * KC + idx] = 1.0f;   // rest of one-hot via memset
  }
#pragma unroll
  for (int m = 1; m < 64; m <<= 1) lp += __shfl_xor(lp, m, 64);
  if (l == 0) lloss[w] = lp;
  __syncthreads();
  if (tid == 0) {
    float t = (lloss[0] + lloss[1] + lloss[2] + lloss[3]) *
              (1.25f / ((float)NROWS * (float)DD));
    atomicAdd(out, t);   // loss = q_latent + 0.25*e_latent = 1.25*mean
  }
}

extern "C" void kernel_launch(void* const* d_in, const int* in_sizes, int n_in,
                              void* d_out, int out_size, void* d_ws, size_t ws_size,
                              hipStream_t stream) {
  const float* X = (const float*)d_in[0];        // c_input [131072,128] fp32
  const float* E = (const float*)d_in[1];        // embedding [1024,128] fp32
  float* out = (float*)d_out;                    // [loss | quantized_st | encodings]
  short* EH = (short*)d_ws;                      // 256 KB bf16-hi fragments
  short* EL = EH + KC * DD;                      // 256 KB bf16-lo fragments
  float* SE = (float*)(EL + KC * DD);            // 4 KB row norms
  // zero the one-hot region with the HW-optimal fill path (stream-ordered,
  // graph-capturable memset node); vq_main then scatters the 1.0s over it.
  size_t encb = (size_t)1 + (size_t)NROWS * DD;
  hipMemsetAsync(out + encb, 0, (size_t)NROWS * KC * sizeof(float), stream);
  vq_prep<<<65, 256, 0, stream>>>(E, EH, EL, SE, out);
  vq_main<<<NROWS / 128, 256, 0, stream>>>(X, E, EH, EL, SE, out);
}

// Round 5
// 832.716 us; speedup vs baseline: 1.1119x; 1.0913x over previous
//
#include <hip/hip_runtime.h>
#include <hip/hip_bf16.h>

#define NROWS 131072
#define KC 1024
#define DD 128
#define MARGIN 1e-3f

typedef __attribute__((ext_vector_type(8))) short short8;
typedef __attribute__((ext_vector_type(4))) float f32x4;

__device__ inline short f2bf_hi(float f) {
  unsigned u = __builtin_bit_cast(unsigned, f);
  u += 0x7fffu + ((u >> 16) & 1u);   // round-to-nearest-even
  return (short)(u >> 16);
}
__device__ inline float bf2f(short s) {
  unsigned u = ((unsigned)(unsigned short)s) << 16;
  return __builtin_bit_cast(float, u);
}

// Prep: embedding -> fragment-ordered bf16 hi/lo + exact row norms; zero loss slot.
// Fragment order: idx = ((c*4 + s)*64 + l), lane l = q*16+n holds e[16c+n][32s+8q+j], j=0..7
__global__ void vq_prep(const float* __restrict__ E, short* __restrict__ EH,
                        short* __restrict__ EL, float* __restrict__ SE,
                        float* __restrict__ out) {
  int b = blockIdx.x, t = threadIdx.x;
  if (b < 64) {
    int idx = b * 256 + t;
    int s = (idx >> 6) & 3, l = idx & 63;
    int c = idx >> 8;
    int q = l >> 4, n = l & 15;
    const float* src = E + (16 * c + n) * DD + 32 * s + 8 * q;
    short8 h, lo;
#pragma unroll
    for (int j = 0; j < 8; ++j) {
      float x = src[j];
      short hb = f2bf_hi(x);
      h[j] = hb;
      lo[j] = f2bf_hi(x - bf2f(hb));
    }
    *(short8*)(EH + idx * 8) = h;
    *(short8*)(EL + idx * 8) = lo;
  } else {
    if (t == 0) out[0] = 0.f;
    for (int k = t; k < KC; k += 256) {
      double acc = 0.0;
      const float* er = E + k * DD;
      for (int i = 0; i < DD; ++i) { double v = (double)er[i]; acc += v * v; }
      SE[k] = (float)acc;
    }
  }
}

// Fused: 3-pass hi/lo bf16 MFMA argmin over 16 rotated chunks of 64 codes,
// top-2 + exact fp64 repair, then in-kernel outputs (st, one-hot, loss).
// ~38 KB LDS -> 4 blocks/CU (16 waves) for overlap.
__global__ __launch_bounds__(256, 4) void vq_main(
    const float* __restrict__ X, const float* __restrict__ E,
    const short* __restrict__ EH, const short* __restrict__ EL,
    const float* __restrict__ SE, float* __restrict__ out) {
  __shared__ __align__(16) short lbh[8192];   // 16 KB: B-hi chunk
  __shared__ __align__(16) short lbl[8192];   // 16 KB: B-lo chunk
  __shared__ __align__(16) float lse[KC];     // 4 KB: |e|^2
  __shared__ int lidx[128];
  __shared__ int lflag[128];
  __shared__ int lany;
  __shared__ float lx[128];
  __shared__ float lrv[4];
  __shared__ int lri[4];
  __shared__ float lsx;
  __shared__ float lloss[4];

  const int tid = threadIdx.x;
  const int w = tid >> 6, l = tid & 63, q = l >> 4, n = l & 15;
  const int row_base = blockIdx.x * 128;
  const int rot = blockIdx.x & 15;            // decorrelate chunk traffic across blocks
  if (tid == 0) lany = 0;
  *(f32x4*)(lse + tid * 4) = *(const f32x4*)(SE + tid * 4);   // 256 thr x 16 B = 4 KB

  // ---- A fragments: wave w owns rows row_base+32w .. +32 (2 tiles of 16) ----
  short8 ah[2][4], al[2][4];
#pragma unroll
  for (int mt = 0; mt < 2; ++mt) {
    const float* xp = X + (row_base + 32 * w + 16 * mt + n) * DD + 8 * q;
#pragma unroll
    for (int s = 0; s < 4; ++s) {
      f32x4 x0 = *(const f32x4*)(xp + 32 * s);
      f32x4 x1 = *(const f32x4*)(xp + 32 * s + 4);
#pragma unroll
      for (int j = 0; j < 4; ++j) {
        short hb = f2bf_hi(x0[j]);
        ah[mt][s][j] = hb;
        al[mt][s][j] = f2bf_hi(x0[j] - bf2f(hb));
        short hb2 = f2bf_hi(x1[j]);
        ah[mt][s][j + 4] = hb2;
        al[mt][s][j + 4] = f2bf_hi(x1[j] - bf2f(hb2));
      }
    }
  }

  // per-lane running top-2 (score = dot - |e|^2/2, maximize) per row-slot (mt,reg)
  float bestv[8], secv[8];
  int besti[8];
#pragma unroll
  for (int i = 0; i < 8; ++i) { bestv[i] = -3e38f; secv[i] = -3e38f; besti[i] = 0; }

  for (int cc = 0; cc < 16; ++cc) {
    const int ccr = (cc + rot) & 15;
    {  // stage B chunk (16 KB hi + 16 KB lo) into LDS
      const short8* gh = (const short8*)(EH + ccr * 8192);
      const short8* gl = (const short8*)(EL + ccr * 8192);
      short8* dh = (short8*)lbh;
      short8* dl = (short8*)lbl;
#pragma unroll
      for (int i = 0; i < 4; ++i) {
        int u = i * 256 + tid;
        dh[u] = gh[u];
        dl[u] = gl[u];
      }
    }
    __syncthreads();

    f32x4 acc[2][4];
#pragma unroll
    for (int mt = 0; mt < 2; ++mt)
#pragma unroll
      for (int nt = 0; nt < 4; ++nt) acc[mt][nt] = (f32x4){0.f, 0.f, 0.f, 0.f};

#pragma unroll
    for (int nt = 0; nt < 4; ++nt) {
#pragma unroll
      for (int s = 0; s < 4; ++s) {
        short8 bh  = *(const short8*)(lbh + ((nt * 4 + s) * 64 + l) * 8);
        short8 blo = *(const short8*)(lbl + ((nt * 4 + s) * 64 + l) * 8);
        acc[0][nt] = __builtin_amdgcn_mfma_f32_16x16x32_bf16(ah[0][s], bh,  acc[0][nt], 0, 0, 0);
        acc[1][nt] = __builtin_amdgcn_mfma_f32_16x16x32_bf16(ah[1][s], bh,  acc[1][nt], 0, 0, 0);
        acc[0][nt] = __builtin_amdgcn_mfma_f32_16x16x32_bf16(al[0][s], bh,  acc[0][nt], 0, 0, 0);
        acc[1][nt] = __builtin_amdgcn_mfma_f32_16x16x32_bf16(al[1][s], bh,  acc[1][nt], 0, 0, 0);
        acc[0][nt] = __builtin_amdgcn_mfma_f32_16x16x32_bf16(ah[0][s], blo, acc[0][nt], 0, 0, 0);
        acc[1][nt] = __builtin_amdgcn_mfma_f32_16x16x32_bf16(ah[1][s], blo, acc[1][nt], 0, 0, 0);
      }
    }
    __syncthreads();  // LDS reuse next chunk

    // fold chunk scores into running top-2 (C layout: col = lane&15, row = quad*4+reg)
#pragma unroll
    for (int nt = 0; nt < 4; ++nt) {
      int k = ccr * 64 + nt * 16 + n;
      float hse = 0.5f * lse[k];
#pragma unroll
      for (int mt = 0; mt < 2; ++mt)
#pragma unroll
        for (int r = 0; r < 4; ++r) {
          float sc = acc[mt][nt][r] - hse;
          int slot = mt * 4 + r;
          bool gt = sc > bestv[slot];
          secv[slot] = gt ? bestv[slot] : fmaxf(secv[slot], sc);
          if (gt) { bestv[slot] = sc; besti[slot] = k; }
        }
    }
  }

  // cross-lane top-2 merge over the 16 column-lanes of each quad (disjoint k-sets)
#pragma unroll
  for (int slot = 0; slot < 8; ++slot) {
    float v = bestv[slot], s2 = secv[slot];
    int bi = besti[slot];
#pragma unroll
    for (int m = 1; m <= 8; m <<= 1) {
      float v2 = __shfl_xor(v, m, 64);
      float sv2 = __shfl_xor(s2, m, 64);
      int i2 = __shfl_xor(bi, m, 64);
      float ns = fmaxf(fminf(v, v2), fmaxf(s2, sv2));
      if (v2 > v || (v2 == v && i2 < bi)) { v = v2; bi = i2; }
      s2 = ns;
    }
    if (n == 0) {
      int mt = slot >> 2, r = slot & 3;
      int rl = 32 * w + 16 * mt + 4 * q + r;
      int f = (v - s2) <= MARGIN;
      lidx[rl] = bi;
      lflag[rl] = f;
      if (f) lany = 1;
    }
  }
  __syncthreads();

  // ---- repair flagged rows: exact fp64 dots, numpy-rounding-emulated distances ----
  if (lany) {
    for (int rl = 0; rl < 128; ++rl) {
      if (lflag[rl] == 0) continue;           // uniform branch (LDS value)
      if (tid < DD) lx[tid] = X[(row_base + rl) * DD + tid];
      __syncthreads();
      if (tid < 64) {                         // sx: row-constant -> argmin-invariant
        double v0 = lx[tid], v1 = lx[tid + 64];
        double s = v0 * v0 + v1 * v1;
#pragma unroll
        for (int m = 1; m < 64; m <<= 1) s += __shfl_xor(s, m, 64);
        if (tid == 0) lsx = (float)s;
      }
      __syncthreads();
      float dmin = 3e38f; int kmin = 0;
      for (int kk = tid; kk < KC; kk += 256) {
        double dot = 0.0;
        const float* er = E + kk * DD;
        for (int i = 0; i < DD; ++i) dot += (double)lx[i] * (double)er[i];
        float a = lsx + lse[kk];
        float b2 = (float)(2.0 * dot);
        float dnp = a - b2;                   // RN(RN(sx+se) - RN(2 dot)) like np
        if (dnp < dmin) { dmin = dnp; kmin = kk; }
      }
#pragma unroll
      for (int m = 1; m < 64; m <<= 1) {      // wave argmin (smaller-index tiebreak)
        float v2 = __shfl_xor(dmin, m, 64);
        int k2 = __shfl_xor(kmin, m, 64);
        if (v2 < dmin || (v2 == dmin && k2 < kmin)) { dmin = v2; kmin = k2; }
      }
      if (l == 0) { lrv[w] = dmin; lri[w] = kmin; }
      __syncthreads();
      if (tid == 0) {
        float dm = lrv[0]; int km = lri[0];
#pragma unroll
        for (int t2 = 1; t2 < 4; ++t2)
          if (lrv[t2] < dm || (lrv[t2] == dm && lri[t2] < km)) { dm = lrv[t2]; km = lri[t2]; }
        lidx[rl] = km;
      }
      __syncthreads();
    }
  }
  __syncthreads();

  // ---- outputs: loss partial, quantized_st, one-hot encodings (in-kernel) ----
  float lp = 0.f;
  const int encb = 1 + NROWS * DD;
  for (int rl = w; rl < 128; rl += 4) {
    int row = row_base + rl;
    int idx = lidx[rl];
    float x0 = X[row * DD + l];
    float x1 = X[row * DD + 64 + l];
    float e0 = E[idx * DD + l];
    float e1 = E[idx * DD + 64 + l];
    float d0 = e0 - x0, d1 = e1 - x1;
    __builtin_nontemporal_store(x0 + d0, out + 1 + row * DD + l);       // straight-through
    __builtin_nontemporal_store(x1 + d1, out + 1 + row * DD + 64 + l);
    lp += d0 * d0 + d1 * d1;
    float* ob = out + encb + row * KC;      // element offset = 1 mod 4
    if (l < 3) __builtin_nontemporal_store((l == idx) ? 1.f : 0.f, ob + l);
    for (int c = l; c < 255; c += 64) {     // ob+3 is 16B-aligned
      int eb = 3 + 4 * c;
      f32x4 v;
      v[0] = (eb     == idx) ? 1.f : 0.f;
      v[1] = (eb + 1 == idx) ? 1.f : 0.f;
      v[2] = (eb + 2 == idx) ? 1.f : 0.f;
      v[3] = (eb + 3 == idx) ? 1.f : 0.f;
      __builtin_nontemporal_store(v, (f32x4*)(ob + eb));
    }
    if (l == 63) __builtin_nontemporal_store((1023 == idx) ? 1.f : 0.f, ob + 1023);
  }
#pragma unroll
  for (int m = 1; m < 64; m <<= 1) lp += __shfl_xor(lp, m, 64);
  if (l == 0) lloss[w] = lp;
  __syncthreads();
  if (tid == 0) {
    float t = (lloss[0] + lloss[1] + lloss[2] + lloss[3]) *
              (1.25f / ((float)NROWS * (float)DD));
    atomicAdd(out, t);   // loss = q_latent + 0.25*e_latent = 1.25*mean
  }
}

extern "C" void kernel_launch(void* const* d_in, const int* in_sizes, int n_in,
                              void* d_out, int out_size, void* d_ws, size_t ws_size,
                              hipStream_t stream) {
  const float* X = (const float*)d_in[0];        // c_input [131072,128] fp32
  const float* E = (const float*)d_in[1];        // embedding [1024,128] fp32
  float* out = (float*)d_out;                    // [loss | quantized_st | encodings]
  short* EH = (short*)d_ws;                      // 256 KB bf16-hi fragments
  short* EL = EH + KC * DD;                      // 256 KB bf16-lo fragments
  float* SE = (float*)(EL + KC * DD);            // 4 KB row norms
  vq_prep<<<65, 256, 0, stream>>>(E, EH, EL, SE, out);
  vq_main<<<NROWS / 128, 256, 0, stream>>>(X, E, EH, EL, SE, out);
}